// Round 6
// baseline (5384.254 us; speedup 1.0000x reference)
//
#include <hip/hip_runtime.h>
#include <math.h>
#include <stdint.h>

// Problem constants
#define B_ROWS 512
#define H_UNITS 16384
#define K_IN 2048
#define K_SEL 64
#define QPT 16  // keys per thread = 16384 / 1024
#define CAND_MAX 2048
#define PIVOT_NEED 160u
#define SWZ(b) ((b) ^ (((b) >> 5) & 31))
// Observational-equivalence clamp: for 0 < a <= 2^-26, rn(1-a)=1.0 exactly and
// rn(rn(0.95a)+1)=1.0 exactly (ties-to-even), and decay keeps a in the zone --
// so a behaves exactly like 0 forever. Clamping is EXACT, and bounds replay.
#define CLAMP26 1.4901161193847656e-8f

// ---------------------------------------------------------------------------
// Kernel 1: encoding = inputs @ W^T  (unchanged, exactness-validated)
// ---------------------------------------------------------------------------
__global__ __launch_bounds__(256) void gemm_kernel(const float* __restrict__ A,
                                                   const float* __restrict__ W,
                                                   float* __restrict__ C) {
  __shared__ __align__(16) float As[64][68];
  __shared__ __align__(16) float Bs[64][68];
  const int tid = threadIdx.x;
  const int tx = tid & 15, ty = tid >> 4;
  const int bm = blockIdx.y * 64, bn = blockIdx.x * 64;

  double accd[16];
#pragma unroll
  for (int i = 0; i < 16; ++i) accd[i] = 0.0;

  const float* Ab = A + (size_t)bm * K_IN;
  const float* Wb = W + (size_t)bn * K_IN;

  for (int k0 = 0; k0 < K_IN; k0 += 64) {
#pragma unroll
    for (int p = 0; p < 4; ++p) {
      int id = p * 256 + tid;
      int m = id >> 4;
      int kq = (id & 15) << 2;
      float4 a = *reinterpret_cast<const float4*>(Ab + (size_t)m * K_IN + k0 + kq);
      As[kq + 0][m] = a.x; As[kq + 1][m] = a.y; As[kq + 2][m] = a.z; As[kq + 3][m] = a.w;
      float4 b = *reinterpret_cast<const float4*>(Wb + (size_t)m * K_IN + k0 + kq);
      Bs[kq + 0][m] = b.x; Bs[kq + 1][m] = b.y; Bs[kq + 2][m] = b.z; Bs[kq + 3][m] = b.w;
    }
    __syncthreads();

    float accf[16];
#pragma unroll
    for (int i = 0; i < 16; ++i) accf[i] = 0.0f;

#pragma unroll 16
    for (int kk = 0; kk < 64; ++kk) {
      float4 av = *reinterpret_cast<const float4*>(&As[kk][ty << 2]);
      float4 bv = *reinterpret_cast<const float4*>(&Bs[kk][tx << 2]);
      accf[0]  += av.x * bv.x; accf[1]  += av.x * bv.y; accf[2]  += av.x * bv.z; accf[3]  += av.x * bv.w;
      accf[4]  += av.y * bv.x; accf[5]  += av.y * bv.y; accf[6]  += av.y * bv.z; accf[7]  += av.y * bv.w;
      accf[8]  += av.z * bv.x; accf[9]  += av.z * bv.y; accf[10] += av.z * bv.z; accf[11] += av.z * bv.w;
      accf[12] += av.w * bv.x; accf[13] += av.w * bv.y; accf[14] += av.w * bv.z; accf[15] += av.w * bv.w;
    }
#pragma unroll
    for (int i = 0; i < 16; ++i) accd[i] += (double)accf[i];
    __syncthreads();
  }

#pragma unroll
  for (int i = 0; i < 4; ++i) {
    size_t rowoff = (size_t)(bm + (ty << 2) + i) * H_UNITS + bn + (tx << 2);
    float4 o;
    o.x = (float)accd[i * 4 + 0]; o.y = (float)accd[i * 4 + 1];
    o.z = (float)accd[i * 4 + 2]; o.w = (float)accd[i * 4 + 3];
    *reinterpret_cast<float4*>(C + rowoff) = o;
  }
}

// ---------------------------------------------------------------------------
__device__ __forceinline__ unsigned int orderable(float x) {
  unsigned int u = __float_as_uint(x);
  return u ^ ((u & 0x80000000u) ? 0xFFFFFFFFu : 0x80000000u);
}

__device__ __forceinline__ unsigned long long make_key(float r, int j) {
  unsigned int u = orderable(r);
  return (((unsigned long long)u) << 14) | (unsigned long long)(16383 - j);
}

// ---------------------------------------------------------------------------
// Serial suffix bucket find (validated) -- slow3 path only.
// ---------------------------------------------------------------------------
__device__ __forceinline__ void suffix_find(const unsigned int* hist, int CH, int need,
                                            int tid, int* s_b, int* s_above) {
  if (tid < 64) {
    unsigned int s = 0;
    for (int q = 0; q < CH; ++q) s += hist[tid * CH + q];
#pragma unroll
    for (int d = 1; d < 64; d <<= 1) {
      unsigned int o = __shfl_down(s, d);
      if (tid + d < 64) s += o;
    }
    unsigned int snext = __shfl_down(s, 1);
    if (tid == 63) snext = 0;
    bool cross = (s >= (unsigned int)need) && (snext < (unsigned int)need);
    unsigned long long bal = __ballot(cross);
    int g = __ffsll(bal) - 1;
    if (tid == g) {
      unsigned int acc = snext;
      int b = g * CH;
      for (int q = CH - 1; q >= 0; --q) {
        unsigned int c = hist[g * CH + q];
        if (acc + c >= (unsigned int)need) { b = g * CH + q; break; }
        acc += c;
      }
      *s_b = b; *s_above = (int)acc;
    }
  }
}

// ---------------------------------------------------------------------------
// In-wave suffix find over 2048 swizzled buckets, TWO replicas (validated).
// ---------------------------------------------------------------------------
__device__ __forceinline__ void wave_find2048(const unsigned int* ha, const unsigned int* hb,
                                              unsigned int need, int tid,
                                              int* s_b, unsigned int* s_above) {
  unsigned int s = 0;
  const int base = tid << 5;
#pragma unroll
  for (int q = 0; q < 32; ++q) {
    int b = base + q;
    int a = SWZ(b);
    s += ha[a] + hb[a];
  }
  unsigned int si = s;
#pragma unroll
  for (int d = 1; d < 64; d <<= 1) {
    unsigned int o = __shfl_down(si, d);
    if (tid + d < 64) si += o;
  }
  unsigned int snext = __shfl_down(si, 1);
  if (tid == 63) snext = 0u;
  bool cross = (si >= need) && (snext < need);
  unsigned long long bal = __ballot(cross);
  int g = __ffsll(bal) - 1;
  unsigned int sng = __shfl(snext, g);
  unsigned int c;
  {
    int b = (g << 5) + (tid & 31);
    int a = SWZ(b);
    c = ha[a] + hb[a];
  }
  unsigned int ti2 = c;
#pragma unroll
  for (int d = 1; d < 32; d <<= 1) {
    unsigned int o = __shfl_down(ti2, d);
    if ((tid & 31) + d < 32) ti2 += o;
  }
  unsigned int incl = sng + ti2;
  unsigned int incln = __shfl_down(incl, 1);
  if ((tid & 31) == 31) incln = sng;
  bool cr2 = (tid < 32) && (incl >= need) && (incln < need);
  unsigned long long bal2 = __ballot(cr2);
  int q2 = __ffsll(bal2) - 1;
  if (tid == q2) { *s_b = (g << 5) + q2; *s_above = incln; }
}

// ---------------------------------------------------------------------------
// Same find, SINGLE replica (tier-2 use, validated).
// ---------------------------------------------------------------------------
__device__ __forceinline__ void wave_find_single(const unsigned int* h, unsigned int need,
                                                 int tid, int* s_b, unsigned int* s_above) {
  unsigned int s = 0;
  const int base = tid << 5;
#pragma unroll
  for (int q = 0; q < 32; ++q) s += h[SWZ(base + q)];
  unsigned int si = s;
#pragma unroll
  for (int d = 1; d < 64; d <<= 1) {
    unsigned int o = __shfl_down(si, d);
    if (tid + d < 64) si += o;
  }
  unsigned int snext = __shfl_down(si, 1);
  if (tid == 63) snext = 0u;
  bool cross = (si >= need) && (snext < need);
  unsigned long long bal = __ballot(cross);
  int g = __ffsll(bal) - 1;
  unsigned int sng = __shfl(snext, g);
  unsigned int c = h[SWZ((g << 5) + (tid & 31))];
  unsigned int ti2 = c;
#pragma unroll
  for (int d = 1; d < 32; d <<= 1) {
    unsigned int o = __shfl_down(ti2, d);
    if ((tid & 31) + d < 32) ti2 += o;
  }
  unsigned int incl = sng + ti2;
  unsigned int incln = __shfl_down(incl, 1);
  if ((tid & 31) == 31) incln = sng;
  bool cr2 = (tid < 32) && (incl >= need) && (incln < need);
  unsigned long long bal2 = __ballot(cr2);
  int q2 = __ffsll(bal2) - 1;
  if (tid == q2) { *s_b = (g << 5) + q2; *s_above = incln; }
}

// ---------------------------------------------------------------------------
// Wave0 refine over packed keys in cand[rb..rb+Cc), ping-pong (rb ^= 2048).
// Takes `needc` largest (key desc; idx-asc tiebreak via packing). tid<64.
// ---------------------------------------------------------------------------
__device__ __forceinline__ void wave_refine_pp(unsigned long long* cand, unsigned int* hist128,
                                               int Cc, int needc, int startShift,
                                               int* srow, int* selJ,
                                               int* s_nsel, int* s_wtmp, int rb) {
  const int tid = threadIdx.x;  // < 64
  int shift = startShift;
  while (true) {
    if (Cc <= needc) {
      for (int s = tid; s < Cc; s += 64) {
        unsigned long long k = cand[rb + s];
        int j = 16383 - (int)(k & 0x3FFFull);
        int slot = atomicAdd(s_nsel, 1);
        srow[slot] = j; selJ[slot] = j;
      }
      break;
    }
    hist128[tid] = 0u;
    hist128[tid + 64] = 0u;
    if (tid == 0) *s_wtmp = 0;
    asm volatile("s_waitcnt lgkmcnt(0)" ::: "memory");
    for (int s = tid; s < Cc; s += 64) {
      int ch = (int)((cand[rb + s] >> shift) & 127ull);
      atomicAdd(&hist128[ch], 1u);
    }
    asm volatile("s_waitcnt lgkmcnt(0)" ::: "memory");
    unsigned int c0 = hist128[2 * tid];
    unsigned int c1 = hist128[2 * tid + 1];
    unsigned int ps = c0 + c1;
#pragma unroll
    for (int d = 1; d < 64; d <<= 1) {
      unsigned int o = __shfl_down(ps, d);
      if (tid + d < 64) ps += o;
    }
    unsigned int incl = ps;
    unsigned int incln = __shfl_down(incl, 1);
    if (tid == 63) incln = 0u;
    unsigned int smid = incl - c0;
    bool crossHi = (smid >= (unsigned int)needc) && (incln < (unsigned int)needc);
    bool crossLo = (incl >= (unsigned int)needc) && (smid < (unsigned int)needc);
    unsigned long long bal = __ballot(crossHi || crossLo);
    int gl = __ffsll(bal) - 1;
    int hiF = __shfl((int)crossHi, gl);
    int vstar = 2 * gl + hiF;
    unsigned int aboveCh = (unsigned int)__shfl((int)(hiF ? incln : smid), gl);
    int wb = rb ^ 2048;
    for (int s = tid; s < Cc; s += 64) {
      unsigned long long k = cand[rb + s];
      int ch = (int)((k >> shift) & 127ull);
      if (ch > vstar) {
        int j = 16383 - (int)(k & 0x3FFFull);
        int slot = atomicAdd(s_nsel, 1);
        srow[slot] = j; selJ[slot] = j;
      } else if (ch == vstar) {
        int p = atomicAdd(s_wtmp, 1);
        cand[wb + p] = k;
      }
    }
    asm volatile("s_waitcnt lgkmcnt(0)" ::: "memory");
    needc -= (int)aboveCh;
    Cc = *s_wtmp;
    rb = wb;
    shift = (shift >= 7) ? shift - 7 : 0;
  }
}

// ---------------------------------------------------------------------------
// Kernel 1.5: per-row candidate precompute (unchanged, validated).
// hdr[4r] = cnt, +1 = bnd, +2 = shift, +3 = theta (uninhibited count >= 160).
// ---------------------------------------------------------------------------
__global__ __launch_bounds__(1024) void precomp_cand(const float* __restrict__ enc,
                                                     unsigned long long* __restrict__ rec,
                                                     unsigned int* __restrict__ hdr) {
  const int row = blockIdx.x;
  const int tid = threadIdx.x;
  __shared__ unsigned int hA[2048], hB[2048], h2a[2048], h2b[2048];
  __shared__ int s_b1; __shared__ unsigned int s_ab1;
  __shared__ int s_b2; __shared__ unsigned int s_ab2;
  __shared__ int s_cnt;
  __shared__ unsigned int s_omax;
  const float* erow = enc + (size_t)row * H_UNITS;

  unsigned int ob[QPT], eb[QPT];
  for (int i = tid; i < 2048; i += 1024) { hA[i] = 0u; hB[i] = 0u; h2a[i] = 0u; h2b[i] = 0u; }
  if (tid == 0) { s_cnt = 0; s_omax = 0u; }
  unsigned int lmax = 0u;
#pragma unroll
  for (int q = 0; q < QPT; ++q) {
    int j = q * 1024 + tid;
    float e = erow[j];
    eb[q] = __float_as_uint(e);
    ob[q] = orderable(fabsf(e));
    if (ob[q] > lmax) lmax = ob[q];
  }
  __syncthreads();

  atomicMax(&s_omax, lmax);
  unsigned int* hrep = ((tid >> 6) & 1) ? hB : hA;
#pragma unroll
  for (int q = 0; q < QPT; ++q) {
    int b = (int)(ob[q] >> 21);
    atomicAdd(&hrep[SWZ(b)], 1u);
  }
  __syncthreads();
  if (tid < 64) wave_find2048(hA, hB, 1024u, tid, &s_b1, &s_ab1);
  __syncthreads();

  const unsigned int b1 = (unsigned int)s_b1;
  const unsigned int need2 = 1024u - s_ab1;
  unsigned int* h2rep = ((tid >> 6) & 1) ? h2b : h2a;
#pragma unroll
  for (int q = 0; q < QPT; ++q) {
    if ((ob[q] >> 21) == b1) {
      int b = (int)((ob[q] >> 10) & 0x7FFu);
      atomicAdd(&h2rep[SWZ(b)], 1u);
    }
  }
  __syncthreads();
  if (tid < 64) wave_find2048(h2a, h2b, need2, tid, &s_b2, &s_ab2);
  __syncthreads();

  const unsigned int bnd = (b1 << 21) | ((unsigned int)s_b2 << 10);
#pragma unroll
  for (int q = 0; q < QPT; ++q) {
    if (ob[q] >= bnd) {
      int p = atomicAdd(&s_cnt, 1);
      if (p < CAND_MAX)
        rec[(size_t)row * CAND_MAX + p] =
            (((unsigned long long)eb[q]) << 32) | (unsigned long long)(q * 1024 + tid);
    }
  }
  for (int i = tid; i < 2048; i += 1024) { h2a[i] = 0u; h2b[i] = 0u; }
  __syncthreads();

  const unsigned int span = s_omax - bnd;
  const int bitpos = (span == 0u) ? -1 : (31 - __clz((int)span));
  const unsigned int shf = (bitpos > 10) ? (unsigned int)(bitpos - 10) : 0u;
#pragma unroll
  for (int q = 0; q < QPT; ++q) {
    if (ob[q] >= bnd) {
      int bb = (int)((ob[q] - bnd) >> shf);
      atomicAdd(&h2rep[SWZ(bb)], 1u);
    }
  }
  __syncthreads();
  if (tid < 64) wave_find2048(h2a, h2b, PIVOT_NEED, tid, &s_b2, &s_ab2);
  __syncthreads();
  if (tid == 0) {
    hdr[4 * row + 0] = (unsigned int)s_cnt;
    hdr[4 * row + 1] = bnd;
    hdr[4 * row + 2] = shf;
    hdr[4 * row + 3] = bnd + ((unsigned int)s_b2 << shf);  // theta
  }
}

// ---------------------------------------------------------------------------
// Kernel 2: pivot scan with LAZY inhibition (Ai value + Ts timestamp).
// Fast path per step (3 barriers):
//  A (all): for <=2 candidate slots: lazy replay a to time t (exact rn(0.95a)
//     chain, clamp at 2^-26 which is observationally exact), write back;
//     key o; o>=theta -> ballot-aggregated append to cand + h256 atomic.  B1
//  B: wave0 ONLY: 256-bin suffix find (registers) -> bstar; one list scan
//     with ballot-aggregated emits (>bstar) and tie-collect (==bstar);
//     finish ties via take-all / tournament / refine. All counts in regs. B2
//  C: tid<64: selected j (already at time t): Ai=rn(rn(0.95a)+1), Ts=t+1;
//     others zero h256 / reset scalars.                                   B3
// Exactness: selected have o >= theta > all non-candidates (r<=|e|<bnd<=theta
// strict); excluded candidates o < selected min; lazy replay is the literal
// np recurrence; clamp proven observationally identical. Cc<64 -> tier2;
// !rowfast or tier2-b1==0 -> tier3 full-row (both validated paths).
// ---------------------------------------------------------------------------
__global__ __launch_bounds__(1024) void scan_cand(const float* __restrict__ enc,
                                                  const unsigned long long* __restrict__ rec,
                                                  const unsigned int* __restrict__ hdr,
                                                  int* __restrict__ seli) {
  const int tid = threadIdx.x;
  __shared__ float Ai[H_UNITS];                 // 64 KB lazy inhib value
  __shared__ unsigned short Ts[H_UNITS];        // 32 KB timestamp
  __shared__ __align__(16) unsigned int h256[256];
  __shared__ unsigned int fine[2048];           // tier2 hist / tier3 replica A
  __shared__ unsigned int histB[2048];          // tier3 replica B / slow3
  __shared__ unsigned long long cand[4096];     // list [0,2048) + ties [2048,4096)
  __shared__ unsigned int hist128[128];
  __shared__ int selJ[64];
  __shared__ int s_b1, s_nsel, s_c2, s_wtmp;
  __shared__ int s_ccnt;
  __shared__ unsigned int s_above;
  __shared__ int s_b2, s_ab2, s_b3, s_ab3, s_tiecnt;

  // init
#pragma unroll
  for (int q = 0; q < QPT; ++q) { Ai[q * 1024 + tid] = 0.0f; Ts[q * 1024 + tid] = 0; }
  fine[tid] = 0u; fine[1024 + tid] = 0u;
  histB[tid] = 0u; histB[1024 + tid] = 0u;
  if (tid < 256) h256[tid] = 0u;
  if (tid == 0) { s_nsel = 0; s_ccnt = 0; s_c2 = 0; s_wtmp = 0; }
  __syncthreads();

  unsigned long long pre0 = rec[tid];
  unsigned long long pre1 = rec[1024 + tid];
  unsigned int preCnt = hdr[0];
  unsigned int preBnd = hdr[1];
  unsigned int preShf = hdr[2];
  unsigned int preTheta = hdr[3];

  const int lane = tid & 63;
  const unsigned long long ltm = (1ull << lane) - 1ull;

  for (int t = 0; t < B_ROWS; ++t) {
    int* srow = seli + t * 64;
    const unsigned long long r0 = pre0, r1 = pre1;
    const int cnt = (int)preCnt;
    const unsigned int bnd = preBnd;
    const int shift = (int)preShf;
    const unsigned int theta = preTheta;
    const int hs = shift + 3;

    const int tn = (t + 1 < B_ROWS) ? (t + 1) : t;
    pre0 = rec[(size_t)tn * CAND_MAX + tid];
    pre1 = rec[(size_t)tn * CAND_MAX + 1024 + tid];
    preCnt = hdr[4 * tn + 0];
    preBnd = hdr[4 * tn + 1];
    preShf = hdr[4 * tn + 2];
    preTheta = hdr[4 * tn + 3];

    const bool rowfast = (cnt <= CAND_MAX);

    // ---- phase A: lazy replay + keys + ballot-aggregated append ----
    bool v0 = false, v1 = false;
    unsigned int o0 = 0u, o1 = 0u;
    int j0 = 0, j1 = 0;
    unsigned long long key0 = 0ull, key1 = 0ull;
    unsigned int bin0 = 0u, bin1 = 0u;
    bool pred0 = false, pred1 = false;
    if (rowfast) {
      v0 = (tid < cnt);
      v1 = (1024 + tid < cnt);
      if (v0) {
        j0 = (int)(r0 & 0xFFFFull);
        float e = __uint_as_float((unsigned int)(r0 >> 32));
        float a = Ai[j0];
        if (a != 0.0f) {
          int dts = t - (int)Ts[j0];
          if (dts > 0) {
            while (dts-- > 0) {
              a = __fmul_rn(a, 0.95f);
              if (a <= CLAMP26) { a = 0.0f; break; }
            }
            Ai[j0] = a; Ts[j0] = (unsigned short)t;
          }
        }
        float rr = __fmul_rn(fabsf(e), __fsub_rn(1.0f, a));  // np-exact
        o0 = orderable(rr);
        pred0 = (o0 >= theta);
        if (pred0) {
          key0 = (((unsigned long long)(o0 - theta)) << 14) | (unsigned long long)(16383 - j0);
          bin0 = (o0 - theta) >> hs;
        }
      }
      if (v1) {
        j1 = (int)(r1 & 0xFFFFull);
        float e = __uint_as_float((unsigned int)(r1 >> 32));
        float a = Ai[j1];
        if (a != 0.0f) {
          int dts = t - (int)Ts[j1];
          if (dts > 0) {
            while (dts-- > 0) {
              a = __fmul_rn(a, 0.95f);
              if (a <= CLAMP26) { a = 0.0f; break; }
            }
            Ai[j1] = a; Ts[j1] = (unsigned short)t;
          }
        }
        float rr = __fmul_rn(fabsf(e), __fsub_rn(1.0f, a));
        o1 = orderable(rr);
        pred1 = (o1 >= theta);
        if (pred1) {
          key1 = (((unsigned long long)(o1 - theta)) << 14) | (unsigned long long)(16383 - j1);
          bin1 = (o1 - theta) >> hs;
        }
      }
      // one LDS atomic per wave for list slots
      unsigned long long bal0 = __ballot(pred0);
      unsigned long long bal1 = __ballot(pred1);
      int c0 = __popcll(bal0), c1 = __popcll(bal1);
      int base = 0;
      if (lane == 0 && (c0 + c1) > 0) base = atomicAdd(&s_ccnt, c0 + c1);
      base = __shfl(base, 0);
      if (pred0) {
        cand[base + __popcll(bal0 & ltm)] = key0;
        atomicAdd(&h256[bin0], 1u);
      }
      if (pred1) {
        cand[base + c0 + __popcll(bal1 & ltm)] = key1;
        atomicAdd(&h256[bin1], 1u);
      }
    }
    __syncthreads();  // B1

    const int Cc = s_ccnt;
    const bool fastok = rowfast && (Cc >= 64);

    if (fastok) {
      // ---- phase B: wave0 select (register-accounted) ----
      if (tid < 64) {
        uint4 c4 = reinterpret_cast<const uint4*>(h256)[tid];
        unsigned int lsum = c4.x + c4.y + c4.z + c4.w;
        unsigned int si = lsum;
#pragma unroll
        for (int d = 1; d < 64; d <<= 1) {
          unsigned int o = __shfl_down(si, d);
          if (tid + d < 64) si += o;
        }
        unsigned int snext = __shfl_down(si, 1);
        if (tid == 63) snext = 0u;
        bool cross = (si >= 64u) && (snext < 64u);
        unsigned long long bal = __ballot(cross);
        int g = __ffsll(bal) - 1;
        unsigned int acc = snext;
        int bl = tid * 4;
        if (acc + c4.w >= 64u) { bl = tid * 4 + 3; }
        else {
          acc += c4.w;
          if (acc + c4.z >= 64u) { bl = tid * 4 + 2; }
          else {
            acc += c4.z;
            if (acc + c4.y >= 64u) { bl = tid * 4 + 1; }
            else { bl = tid * 4; }
          }
        }
        const unsigned int bstar = (unsigned int)__shfl(bl, g);
        // single scan: ballot-aggregated emit(>b*) and tie-collect(==b*)
        const int ksh = 14 + hs;
        int nsel = 0, ntie = 0;
        for (int s0 = 0; s0 < Cc; s0 += 64) {
          int s = s0 + tid;
          bool inr = (s < Cc);
          unsigned long long k = inr ? cand[s] : 0ull;
          unsigned int bk = (unsigned int)(k >> ksh);
          bool em = inr && (bk > bstar);
          bool ti = inr && (bk == bstar);
          unsigned long long balE = __ballot(em);
          unsigned long long balT = __ballot(ti);
          if (em) {
            int p = nsel + __popcll(balE & ltm);
            int j = 16383 - (int)(k & 0x3FFFull);
            srow[p] = j; selJ[p] = j;
          }
          if (ti) {
            int p = ntie + __popcll(balT & ltm);
            cand[2048 + p] = k;
          }
          nsel += __popcll(balE);
          ntie += __popcll(balT);
        }
        asm volatile("s_waitcnt lgkmcnt(0)" ::: "memory");
        const int tneed = 64 - nsel;   // == ties needed; ntie >= tneed always
        const int Cc2 = ntie;
        if (Cc2 <= tneed) {
          for (int s = tid; s < Cc2; s += 64) {
            unsigned long long k = cand[2048 + s];
            int j = 16383 - (int)(k & 0x3FFFull);
            srow[nsel + s] = j; selJ[nsel + s] = j;
          }
        } else if (Cc2 <= 64 && tneed <= 16) {
          bool alive = (tid < Cc2);
          unsigned long long myk = alive ? cand[2048 + tid] : 0ull;
          for (int r = 0; r < tneed; ++r) {
            unsigned long long v = myk;
#pragma unroll
            for (int d = 32; d >= 1; d >>= 1) {
              unsigned long long o = __shfl_down(v, d);
              if (o > v) v = o;
            }
            v = __shfl(v, 0);
            if (alive && myk == v) {
              int j = 16383 - (int)(myk & 0x3FFFull);
              srow[nsel + r] = j; selJ[nsel + r] = j;
              alive = false; myk = 0ull;
            }
          }
        } else {
          if (lane == 0) s_nsel = nsel;
          asm volatile("s_waitcnt lgkmcnt(0)" ::: "memory");
          wave_refine_pp(cand, hist128, Cc2, tneed, shift + 10, srow, selJ,
                         &s_nsel, &s_wtmp, 2048);
          if (lane == 0) s_wtmp = 0;
        }
      }
      __syncthreads();  // B2

      // ---- phase C: +1 on selected (already replayed to t), housekeeping ----
      if (tid < 64) {
        int j = selJ[tid];
        float a = Ai[j];
        Ai[j] = __fadd_rn(__fmul_rn(a, 0.95f), 1.0f);
        Ts[j] = (unsigned short)(t + 1);
      } else if (tid < 320) {
        h256[tid - 64] = 0u;
      } else if (tid == 320) {
        s_ccnt = 0;
      } else if (tid == 321) {
        s_nsel = 0;
      }
      __syncthreads();  // B3
      continue;
    }

    // =================== TIER 2 / TIER 3 (rare, validated) ===================
    bool do_fullrow = !rowfast;
    if (rowfast) {
      // TIER 2: candidate histogram on register keys (inhib at time t via A)
      if (v0) {
        unsigned int bb = (o0 >= bnd) ? ((o0 - bnd) >> shift) : 0u;
        atomicAdd(&fine[SWZ((int)bb)], 1u);
      }
      if (v1) {
        unsigned int bb = (o1 >= bnd) ? ((o1 - bnd) >> shift) : 0u;
        atomicAdd(&fine[SWZ((int)bb)], 1u);
      }
      __syncthreads();
      if (tid < 64) wave_find_single(fine, 64u, tid, &s_b1, &s_above);
      __syncthreads();
      const int b1v = s_b1;
      if (b1v > 0) {
        const unsigned int basev = bnd + ((unsigned int)b1v << shift);
        if (v0) {
          unsigned int bb = (o0 >= bnd) ? ((o0 - bnd) >> shift) : 0u;
          if ((int)bb > b1v) {
            int slot = atomicAdd(&s_nsel, 1);
            srow[slot] = j0; selJ[slot] = j0;
          } else if ((int)bb == b1v) {
            int p = atomicAdd(&s_c2, 1);
            cand[2048 + p] = (((unsigned long long)(o0 - basev)) << 14) | (unsigned long long)(16383 - j0);
          }
        }
        if (v1) {
          unsigned int bb = (o1 >= bnd) ? ((o1 - bnd) >> shift) : 0u;
          if ((int)bb > b1v) {
            int slot = atomicAdd(&s_nsel, 1);
            srow[slot] = j1; selJ[slot] = j1;
          } else if ((int)bb == b1v) {
            int p = atomicAdd(&s_c2, 1);
            cand[2048 + p] = (((unsigned long long)(o1 - basev)) << 14) | (unsigned long long)(16383 - j1);
          }
        }
        __syncthreads();
        const int Cc2 = s_c2;
        if (tid < 64)
          wave_refine_pp(cand, hist128, Cc2, 64 - s_nsel, shift + 7, srow, selJ,
                         &s_nsel, &s_wtmp, 2048);
        __syncthreads();
      } else {
        fine[tid] = 0u; fine[1024 + tid] = 0u;
        __syncthreads();
        do_fullrow = true;
      }
    }

    if (do_fullrow) {
      // TIER 3: full-row; replay ALL units to time t, then validated select
      const float* erow = enc + (size_t)t * H_UNITS;
      unsigned int ok[QPT];
#pragma unroll
      for (int q = 0; q < QPT; ++q) {
        int j = q * 1024 + tid;
        float a = Ai[j];
        if (a != 0.0f) {
          int dts = t - (int)Ts[j];
          if (dts > 0) {
            while (dts-- > 0) {
              a = __fmul_rn(a, 0.95f);
              if (a <= CLAMP26) { a = 0.0f; break; }
            }
            Ai[j] = a;
          }
        }
        Ts[j] = (unsigned short)t;
        float e = erow[j];
        float rr = __fmul_rn(fabsf(e), __fsub_rn(1.0f, a));
        ok[q] = orderable(rr);
      }
      __syncthreads();
      unsigned int* hrep = ((tid >> 6) & 1) ? histB : fine;
#pragma unroll
      for (int q = 0; q < QPT; ++q) {
        int b = (int)(ok[q] >> 21);
        atomicAdd(&hrep[SWZ(b)], 1u);
      }
      __syncthreads();
      if (tid < 64) wave_find2048(fine, histB, 64u, tid, &s_b1, &s_above);
      __syncthreads();
      const unsigned int fb1 = (unsigned int)s_b1;
#pragma unroll
      for (int q = 0; q < QPT; ++q) {
        unsigned int o = ok[q];
        unsigned int bb = o >> 21;
        int j = q * 1024 + tid;
        if (bb > fb1) {
          int slot = atomicAdd(&s_nsel, 1);
          srow[slot] = j; selJ[slot] = j;
        } else if (bb == fb1) {
          int p = atomicAdd(&s_c2, 1);
          if (p < 2048)
            cand[p] = (((unsigned long long)(o - (fb1 << 21))) << 14) | (unsigned long long)(16383 - j);
        }
      }
      __syncthreads();
      const int Cc0 = s_c2;
      if (Cc0 <= 2048) {
        if (tid < 64)
          wave_refine_pp(cand, hist128, Cc0, 64 - s_nsel, 28, srow, selJ,
                         &s_nsel, &s_wtmp, 0);
        __syncthreads();
      } else {
        // slow 3-pass (proven)
        int need2 = 64 - s_nsel;
        for (int i = tid; i < 2048; i += 1024) fine[i] = 0u;
        histB[tid] = 0u; histB[1024 + tid] = 0u;
        if (tid == 0) s_tiecnt = 0;
        __syncthreads();
#pragma unroll
        for (int q = 0; q < QPT; ++q)
          if ((ok[q] >> 21) == fb1) atomicAdd(&fine[(ok[q] >> 10) & 0x7FFu], 1u);
        __syncthreads();
        suffix_find(fine, 32, need2, tid, &s_b2, &s_ab2);
        __syncthreads();
        const unsigned int pfx = (fb1 << 21) | ((unsigned int)s_b2 << 10);
        const int need3 = need2 - s_ab2;
#pragma unroll
        for (int q = 0; q < QPT; ++q)
          if ((ok[q] & 0xFFFFFC00u) == pfx) atomicAdd(&histB[ok[q] & 0x3FFu], 1u);
        __syncthreads();
        suffix_find(histB, 16, need3, tid, &s_b3, &s_ab3);
        __syncthreads();
        const unsigned int ostar = pfx | (unsigned int)s_b3;
        const int tneed = need3 - s_ab3;
        int* tl = (int*)cand;
#pragma unroll
        for (int q = 0; q < QPT; ++q) {
          unsigned int o = ok[q];
          int j = q * 1024 + tid;
          if (o > ostar && (o >> 21) == fb1) {
            int slot = atomicAdd(&s_nsel, 1);
            srow[slot] = j; selJ[slot] = j;
          } else if (o == ostar) {
            int p = atomicAdd(&s_tiecnt, 1);
            if (p < 1024) tl[p] = j;
          }
        }
        __syncthreads();
        if (tid == 0) {
          int tc = s_tiecnt; if (tc > 1024) tc = 1024;
          for (int k = 0; k < tneed; ++k) {
            int bi = 0x7FFFFFFF, bpos = 0;
            for (int i = 0; i < tc; ++i) {
              int v = tl[i];
              if (v < bi) { bi = v; bpos = i; }
            }
            tl[bpos] = 0x7FFFFFFF;
            selJ[64 - tneed + k] = bi;
            srow[64 - tneed + k] = bi;
          }
        }
        __syncthreads();
      }
    }

    // ---- tier common tail: clean LDS, then +1 on selected (all at time t) ----
    fine[tid] = 0u; fine[1024 + tid] = 0u;
    histB[tid] = 0u; histB[1024 + tid] = 0u;
    if (tid < 256) h256[tid] = 0u;
    if (tid == 256) { s_ccnt = 0; }
    if (tid == 257) { s_nsel = 0; }
    if (tid == 258) { s_c2 = 0; }
    if (tid == 259) { s_wtmp = 0; }
    __syncthreads();
    if (tid < 64) {
      int j = selJ[tid];
      float a = Ai[j];
      Ai[j] = __fadd_rn(__fmul_rn(a, 0.95f), 1.0f);
      Ts[j] = (unsigned short)(t + 1);
    }
    __syncthreads();
  }
}

// ---------------------------------------------------------------------------
// Kernel 2-OLD (ws-gate fallback): validated full-row scan (unchanged).
// ---------------------------------------------------------------------------
__global__ __launch_bounds__(1024) void scan_radix(const float* __restrict__ enc,
                                                   int* __restrict__ seli) {
  const int tid = threadIdx.x;
  __shared__ unsigned int histA[2048];
  __shared__ unsigned int histB[2048];
  __shared__ unsigned int hist128[128];
  __shared__ unsigned int bmap[2][512];
  __shared__ unsigned long long cand[4096];
  __shared__ int s_b1, s_nsel, s_ccnt, s_wtmp;
  __shared__ int s_b2, s_ab2, s_b3, s_ab3, s_tiecnt;
  __shared__ unsigned int s_abU;

  float iv[QPT];
  float ec[QPT];
#pragma unroll
  for (int q = 0; q < QPT; ++q) iv[q] = 0.0f;
#pragma unroll
  for (int q = 0; q < QPT; ++q) ec[q] = enc[q * 1024 + tid];

  for (int t = 0; t < B_ROWS; ++t) {
    const int cur = t & 1;
    unsigned int* bm = bmap[cur];
    int* srow = seli + t * 64;

    for (int i = tid; i < 2048; i += 1024) { histA[i] = 0u; histB[i] = 0u; }
    if (tid < 512) bm[tid] = 0u;
    if (tid == 0) { s_nsel = 0; s_ccnt = 0; }
    unsigned int ok[QPT];
#pragma unroll
    for (int q = 0; q < QPT; ++q) {
      float r = __fmul_rn(fabsf(ec[q]), __fsub_rn(1.0f, iv[q]));
      ok[q] = orderable(r);
    }
    __syncthreads();

    const int tn = (t + 1 < B_ROWS) ? (t + 1) : t;
    const float* nrow = enc + (size_t)tn * H_UNITS;
    float en[QPT];
#pragma unroll
    for (int q = 0; q < QPT; ++q) en[q] = nrow[q * 1024 + tid];

    unsigned int* hrep = ((tid >> 6) & 1) ? histB : histA;
#pragma unroll
    for (int q = 0; q < QPT; ++q) {
      int b = (int)(ok[q] >> 21);
      atomicAdd(&hrep[SWZ(b)], 1u);
    }
    __syncthreads();

    if (tid < 64) wave_find2048(histA, histB, 64u, tid, &s_b1, &s_abU);
    __syncthreads();

    const unsigned int b1 = (unsigned int)s_b1;
#pragma unroll
    for (int q = 0; q < QPT; ++q) {
      unsigned int o = ok[q];
      unsigned int bb = o >> 21;
      if (bb >= b1) {
        int j = q * 1024 + tid;
        if (bb > b1) {
          int slot = atomicAdd(&s_nsel, 1);
          srow[slot] = j;
          atomicOr(&bm[j >> 5], 1u << (j & 31));
        } else {
          int p = atomicAdd(&s_ccnt, 1);
          if (p < 2048)
            cand[p] = (((unsigned long long)o) << 14) | (unsigned long long)(16383 - j);
        }
      }
    }
    __syncthreads();

    const int Cc0 = s_ccnt;
    if (Cc0 <= 2048) {
      if (tid < 64) {
        int needc = 64 - s_nsel;
        int Cc = Cc0;
        int shift = 28;
        int rb = 0;
        while (true) {
          if (Cc <= needc) {
            for (int s = tid; s < Cc; s += 64) {
              unsigned long long k = cand[rb + s];
              int j = 16383 - (int)(k & 0x3FFFull);
              int slot = atomicAdd(&s_nsel, 1);
              srow[slot] = j;
              atomicOr(&bm[j >> 5], 1u << (j & 31));
            }
            break;
          }
          hist128[tid] = 0u;
          hist128[tid + 64] = 0u;
          if (tid == 0) s_wtmp = 0;
          asm volatile("s_waitcnt lgkmcnt(0)" ::: "memory");
          for (int s = tid; s < Cc; s += 64) {
            int ch = (int)((cand[rb + s] >> shift) & 127ull);
            atomicAdd(&hist128[ch], 1u);
          }
          asm volatile("s_waitcnt lgkmcnt(0)" ::: "memory");
          unsigned int c0 = hist128[2 * tid];
          unsigned int c1 = hist128[2 * tid + 1];
          unsigned int ps = c0 + c1;
#pragma unroll
          for (int d = 1; d < 64; d <<= 1) {
            unsigned int o = __shfl_down(ps, d);
            if (tid + d < 64) ps += o;
          }
          unsigned int incl = ps;
          unsigned int incln = __shfl_down(incl, 1);
          if (tid == 63) incln = 0u;
          unsigned int smid = incl - c0;
          bool crossHi = (smid >= (unsigned int)needc) && (incln < (unsigned int)needc);
          bool crossLo = (incl >= (unsigned int)needc) && (smid < (unsigned int)needc);
          unsigned long long bal = __ballot(crossHi || crossLo);
          int gl = __ffsll(bal) - 1;
          int hiF = __shfl((int)crossHi, gl);
          int vstar = 2 * gl + hiF;
          unsigned int aboveCh = (unsigned int)__shfl((int)(hiF ? incln : smid), gl);
          int wb = rb ^ 2048;
          for (int s = tid; s < Cc; s += 64) {
            unsigned long long k = cand[rb + s];
            int ch = (int)((k >> shift) & 127ull);
            if (ch > vstar) {
              int j = 16383 - (int)(k & 0x3FFFull);
              int slot = atomicAdd(&s_nsel, 1);
              srow[slot] = j;
              atomicOr(&bm[j >> 5], 1u << (j & 31));
            } else if (ch == vstar) {
              int p = atomicAdd(&s_wtmp, 1);
              cand[wb + p] = k;
            }
          }
          asm volatile("s_waitcnt lgkmcnt(0)" ::: "memory");
          needc -= (int)aboveCh;
          Cc = s_wtmp;
          rb = wb;
          shift = (shift >= 7) ? shift - 7 : 0;
        }
      }
    } else {
      int need2 = 64 - s_nsel;
      for (int i = tid; i < 2048; i += 1024) histA[i] = 0u;
      histB[tid] = 0u;
      if (tid == 0) s_tiecnt = 0;
      __syncthreads();
#pragma unroll
      for (int q = 0; q < QPT; ++q)
        if ((ok[q] >> 21) == b1) atomicAdd(&histA[(ok[q] >> 10) & 0x7FFu], 1u);
      __syncthreads();
      suffix_find(histA, 32, need2, tid, &s_b2, &s_ab2);
      __syncthreads();
      const unsigned int pfx = (b1 << 21) | ((unsigned int)s_b2 << 10);
      const int need3 = need2 - s_ab2;
#pragma unroll
      for (int q = 0; q < QPT; ++q)
        if ((ok[q] & 0xFFFFFC00u) == pfx) atomicAdd(&histB[ok[q] & 0x3FFu], 1u);
      __syncthreads();
      suffix_find(histB, 16, need3, tid, &s_b3, &s_ab3);
      __syncthreads();
      const unsigned int ostar = pfx | (unsigned int)s_b3;
      const int tneed = need3 - s_ab3;
      int* tl = (int*)cand;
#pragma unroll
      for (int q = 0; q < QPT; ++q) {
        unsigned int o = ok[q];
        int j = q * 1024 + tid;
        if (o > ostar && (o >> 21) == b1) {
          int slot = atomicAdd(&s_nsel, 1);
          srow[slot] = j;
          atomicOr(&bm[j >> 5], 1u << (j & 31));
        } else if (o == ostar) {
          int p = atomicAdd(&s_tiecnt, 1);
          if (p < 1024) tl[p] = j;
        }
      }
      __syncthreads();
      if (tid == 0) {
        int tc = s_tiecnt; if (tc > 1024) tc = 1024;
        for (int k = 0; k < tneed; ++k) {
          int bi = 0x7FFFFFFF, bpos = 0;
          for (int i = 0; i < tc; ++i) {
            int v = tl[i];
            if (v < bi) { bi = v; bpos = i; }
          }
          tl[bpos] = 0x7FFFFFFF;
          bmap[cur][bi >> 5] |= (1u << (bi & 31));
          srow[64 - tneed + k] = bi;
        }
      }
    }
    __syncthreads();

#pragma unroll
    for (int q = 0; q < QPT; ++q) {
      int j = q * 1024 + tid;
      float m = ((bm[j >> 5] >> (j & 31)) & 1u) ? 1.0f : 0.0f;
      iv[q] = __fadd_rn(__fmul_rn(iv[q], 0.95f), m);
      ec[q] = en[q];
    }
    __syncthreads();
  }
}

// ---------------------------------------------------------------------------
// Kernel 3: final top-64 over filtered = enc * mask (unchanged, validated).
// ---------------------------------------------------------------------------
__global__ __launch_bounds__(1024) void final_brute(const int* __restrict__ seli,
                                                    float* __restrict__ out) {
  const int row = blockIdx.x;
  const int tid = threadIdx.x;
  __shared__ unsigned long long wmax[16];
  __shared__ unsigned long long s_win;
  __shared__ int wlist[64];
  __shared__ unsigned int bmap[512];
  const float* erow = out + (size_t)row * H_UNITS;

  if (tid < 512) bmap[tid] = 0u;
  __syncthreads();
  if (tid < 64) {
    int idx = seli[row * 64 + tid];
    atomicOr(&bmap[idx >> 5], 1u << (idx & 31));
  }
  __syncthreads();

  unsigned long long key[16];
  unsigned long long lmax = 0ull;
#pragma unroll
  for (int q = 0; q < 16; ++q) {
    int j = q * 1024 + tid;
    float e = erow[j];
    bool sel = (bmap[j >> 5] >> (j & 31)) & 1u;
    unsigned int eb = __float_as_uint(e);
    float f = __uint_as_float(sel ? eb : (eb & 0x80000000u));  // ±0 keeps sign
    unsigned long long k = make_key(f, j);
    key[q] = k;
    if (k > lmax) lmax = k;
  }
  __syncthreads();

  float4 z = make_float4(0.0f, 0.0f, 0.0f, 0.0f);
  float4* o4 = reinterpret_cast<float4*>(out + (size_t)row * H_UNITS);
  for (int i = tid; i < H_UNITS / 4; i += 1024) o4[i] = z;
  __syncthreads();

  for (int round = 0; round < 64; ++round) {
    unsigned long long v = lmax;
#pragma unroll
    for (int d = 32; d >= 1; d >>= 1) {
      unsigned long long o = __shfl_down(v, d);
      if (o > v) v = o;
    }
    if ((tid & 63) == 0) wmax[tid >> 6] = v;
    __syncthreads();
    if (tid == 0) {
      unsigned long long m = wmax[0];
#pragma unroll
      for (int w = 1; w < 16; ++w)
        if (wmax[w] > m) m = wmax[w];
      s_win = m;
      wlist[round] = 16383 - (int)(m & 0x3FFFull);
    }
    __syncthreads();
    unsigned long long Wk = s_win;
    if (lmax == Wk) {
      unsigned long long nm = 0ull;
#pragma unroll
      for (int q = 0; q < 16; ++q) {
        unsigned long long k = key[q];
        if (k < Wk && k > nm) nm = k;
      }
      lmax = nm;
    }
  }
  __syncthreads();
  if (tid < 64) out[(size_t)row * H_UNITS + wlist[tid]] = 1.0f;
}

// ---------------------------------------------------------------------------
extern "C" void kernel_launch(void* const* d_in, const int* in_sizes, int n_in,
                              void* d_out, int out_size, void* d_ws, size_t ws_size,
                              hipStream_t stream) {
  const float* inputs = (const float*)d_in[0];   // [512][2048] fp32
  const float* W = (const float*)d_in[1];        // [16384][2048] fp32
  float* out = (float*)d_out;                    // [512][16384] fp32 -- also enc scratch
  char* ws = (char*)d_ws;

  // ws layout: [0] seli 128KB | [131072] hdr 8KB | [139264] rec 8MB
  int* seli = (int*)(ws);
  unsigned int* hdr = (unsigned int*)(ws + 131072);
  unsigned long long* rec = (unsigned long long*)(ws + 139264);
  const size_t WS_NEEDED = 139264 + (size_t)B_ROWS * CAND_MAX * 8;  // 8,527,872

  float* enc = out;  // encoding scratch lives in d_out

  gemm_kernel<<<dim3(H_UNITS / 64, B_ROWS / 64), 256, 0, stream>>>(inputs, W, enc);
  if (ws_size >= WS_NEEDED) {
    precomp_cand<<<B_ROWS, 1024, 0, stream>>>(enc, rec, hdr);
    scan_cand<<<1, 1024, 0, stream>>>(enc, rec, hdr, seli);
  } else {
    scan_radix<<<1, 1024, 0, stream>>>(enc, seli);
  }
  final_brute<<<B_ROWS, 1024, 0, stream>>>(seli, out);
}

// Round 7
// 2128.952 us; speedup vs baseline: 2.5291x; 2.5291x over previous
//
#include <hip/hip_runtime.h>
#include <math.h>
#include <stdint.h>

// Problem constants
#define B_ROWS 512
#define H_UNITS 16384
#define K_IN 2048
#define K_SEL 64
#define QPT 16  // keys per thread = 16384 / 1024
#define CAND_MAX 2048
#define PIVOT_NEED 160u
#define SWZ(b) ((b) ^ (((b) >> 5) & 31))

// ---------------------------------------------------------------------------
// Kernel 1: encoding = inputs @ W^T  (unchanged, exactness-validated)
// ---------------------------------------------------------------------------
__global__ __launch_bounds__(256) void gemm_kernel(const float* __restrict__ A,
                                                   const float* __restrict__ W,
                                                   float* __restrict__ C) {
  __shared__ __align__(16) float As[64][68];
  __shared__ __align__(16) float Bs[64][68];
  const int tid = threadIdx.x;
  const int tx = tid & 15, ty = tid >> 4;
  const int bm = blockIdx.y * 64, bn = blockIdx.x * 64;

  double accd[16];
#pragma unroll
  for (int i = 0; i < 16; ++i) accd[i] = 0.0;

  const float* Ab = A + (size_t)bm * K_IN;
  const float* Wb = W + (size_t)bn * K_IN;

  for (int k0 = 0; k0 < K_IN; k0 += 64) {
#pragma unroll
    for (int p = 0; p < 4; ++p) {
      int id = p * 256 + tid;
      int m = id >> 4;
      int kq = (id & 15) << 2;
      float4 a = *reinterpret_cast<const float4*>(Ab + (size_t)m * K_IN + k0 + kq);
      As[kq + 0][m] = a.x; As[kq + 1][m] = a.y; As[kq + 2][m] = a.z; As[kq + 3][m] = a.w;
      float4 b = *reinterpret_cast<const float4*>(Wb + (size_t)m * K_IN + k0 + kq);
      Bs[kq + 0][m] = b.x; Bs[kq + 1][m] = b.y; Bs[kq + 2][m] = b.z; Bs[kq + 3][m] = b.w;
    }
    __syncthreads();

    float accf[16];
#pragma unroll
    for (int i = 0; i < 16; ++i) accf[i] = 0.0f;

#pragma unroll 16
    for (int kk = 0; kk < 64; ++kk) {
      float4 av = *reinterpret_cast<const float4*>(&As[kk][ty << 2]);
      float4 bv = *reinterpret_cast<const float4*>(&Bs[kk][tx << 2]);
      accf[0]  += av.x * bv.x; accf[1]  += av.x * bv.y; accf[2]  += av.x * bv.z; accf[3]  += av.x * bv.w;
      accf[4]  += av.y * bv.x; accf[5]  += av.y * bv.y; accf[6]  += av.y * bv.z; accf[7]  += av.y * bv.w;
      accf[8]  += av.z * bv.x; accf[9]  += av.z * bv.y; accf[10] += av.z * bv.z; accf[11] += av.z * bv.w;
      accf[12] += av.w * bv.x; accf[13] += av.w * bv.y; accf[14] += av.w * bv.z; accf[15] += av.w * bv.w;
    }
#pragma unroll
    for (int i = 0; i < 16; ++i) accd[i] += (double)accf[i];
    __syncthreads();
  }

#pragma unroll
  for (int i = 0; i < 4; ++i) {
    size_t rowoff = (size_t)(bm + (ty << 2) + i) * H_UNITS + bn + (tx << 2);
    float4 o;
    o.x = (float)accd[i * 4 + 0]; o.y = (float)accd[i * 4 + 1];
    o.z = (float)accd[i * 4 + 2]; o.w = (float)accd[i * 4 + 3];
    *reinterpret_cast<float4*>(C + rowoff) = o;
  }
}

// ---------------------------------------------------------------------------
__device__ __forceinline__ unsigned int orderable(float x) {
  unsigned int u = __float_as_uint(x);
  return u ^ ((u & 0x80000000u) ? 0xFFFFFFFFu : 0x80000000u);
}

__device__ __forceinline__ unsigned long long make_key(float r, int j) {
  unsigned int u = orderable(r);
  return (((unsigned long long)u) << 14) | (unsigned long long)(16383 - j);
}

// ---------------------------------------------------------------------------
// Serial suffix bucket find (validated) -- slow3 path only.
// ---------------------------------------------------------------------------
__device__ __forceinline__ void suffix_find(const unsigned int* hist, int CH, int need,
                                            int tid, int* s_b, int* s_above) {
  if (tid < 64) {
    unsigned int s = 0;
    for (int q = 0; q < CH; ++q) s += hist[tid * CH + q];
#pragma unroll
    for (int d = 1; d < 64; d <<= 1) {
      unsigned int o = __shfl_down(s, d);
      if (tid + d < 64) s += o;
    }
    unsigned int snext = __shfl_down(s, 1);
    if (tid == 63) snext = 0;
    bool cross = (s >= (unsigned int)need) && (snext < (unsigned int)need);
    unsigned long long bal = __ballot(cross);
    int g = __ffsll(bal) - 1;
    if (tid == g) {
      unsigned int acc = snext;
      int b = g * CH;
      for (int q = CH - 1; q >= 0; --q) {
        unsigned int c = hist[g * CH + q];
        if (acc + c >= (unsigned int)need) { b = g * CH + q; break; }
        acc += c;
      }
      *s_b = b; *s_above = (int)acc;
    }
  }
}

// ---------------------------------------------------------------------------
// In-wave suffix find over 2048 swizzled buckets, TWO replicas (validated).
// ---------------------------------------------------------------------------
__device__ __forceinline__ void wave_find2048(const unsigned int* ha, const unsigned int* hb,
                                              unsigned int need, int tid,
                                              int* s_b, unsigned int* s_above) {
  unsigned int s = 0;
  const int base = tid << 5;
#pragma unroll
  for (int q = 0; q < 32; ++q) {
    int b = base + q;
    int a = SWZ(b);
    s += ha[a] + hb[a];
  }
  unsigned int si = s;
#pragma unroll
  for (int d = 1; d < 64; d <<= 1) {
    unsigned int o = __shfl_down(si, d);
    if (tid + d < 64) si += o;
  }
  unsigned int snext = __shfl_down(si, 1);
  if (tid == 63) snext = 0u;
  bool cross = (si >= need) && (snext < need);
  unsigned long long bal = __ballot(cross);
  int g = __ffsll(bal) - 1;
  unsigned int sng = __shfl(snext, g);
  unsigned int c;
  {
    int b = (g << 5) + (tid & 31);
    int a = SWZ(b);
    c = ha[a] + hb[a];
  }
  unsigned int ti2 = c;
#pragma unroll
  for (int d = 1; d < 32; d <<= 1) {
    unsigned int o = __shfl_down(ti2, d);
    if ((tid & 31) + d < 32) ti2 += o;
  }
  unsigned int incl = sng + ti2;
  unsigned int incln = __shfl_down(incl, 1);
  if ((tid & 31) == 31) incln = sng;
  bool cr2 = (tid < 32) && (incl >= need) && (incln < need);
  unsigned long long bal2 = __ballot(cr2);
  int q2 = __ffsll(bal2) - 1;
  if (tid == q2) { *s_b = (g << 5) + q2; *s_above = incln; }
}

// ---------------------------------------------------------------------------
// Same find, SINGLE replica (tier-2 use, validated).
// ---------------------------------------------------------------------------
__device__ __forceinline__ void wave_find_single(const unsigned int* h, unsigned int need,
                                                 int tid, int* s_b, unsigned int* s_above) {
  unsigned int s = 0;
  const int base = tid << 5;
#pragma unroll
  for (int q = 0; q < 32; ++q) s += h[SWZ(base + q)];
  unsigned int si = s;
#pragma unroll
  for (int d = 1; d < 64; d <<= 1) {
    unsigned int o = __shfl_down(si, d);
    if (tid + d < 64) si += o;
  }
  unsigned int snext = __shfl_down(si, 1);
  if (tid == 63) snext = 0u;
  bool cross = (si >= need) && (snext < need);
  unsigned long long bal = __ballot(cross);
  int g = __ffsll(bal) - 1;
  unsigned int sng = __shfl(snext, g);
  unsigned int c = h[SWZ((g << 5) + (tid & 31))];
  unsigned int ti2 = c;
#pragma unroll
  for (int d = 1; d < 32; d <<= 1) {
    unsigned int o = __shfl_down(ti2, d);
    if ((tid & 31) + d < 32) ti2 += o;
  }
  unsigned int incl = sng + ti2;
  unsigned int incln = __shfl_down(incl, 1);
  if ((tid & 31) == 31) incln = sng;
  bool cr2 = (tid < 32) && (incl >= need) && (incln < need);
  unsigned long long bal2 = __ballot(cr2);
  int q2 = __ffsll(bal2) - 1;
  if (tid == q2) { *s_b = (g << 5) + q2; *s_above = incln; }
}

// ---------------------------------------------------------------------------
// Wave0 refine over packed keys in cand[rb..rb+Cc), ping-pong (rb ^= 2048).
// Takes `needc` largest (key desc; idx-asc tiebreak via packing). tid<64.
// ---------------------------------------------------------------------------
__device__ __forceinline__ void wave_refine_pp(unsigned long long* cand, unsigned int* hist128,
                                               int Cc, int needc, int startShift,
                                               int* srow, int* selJ,
                                               int* s_nsel, int* s_wtmp, int rb) {
  const int tid = threadIdx.x;  // < 64
  int shift = startShift;
  while (true) {
    if (Cc <= needc) {
      for (int s = tid; s < Cc; s += 64) {
        unsigned long long k = cand[rb + s];
        int j = 16383 - (int)(k & 0x3FFFull);
        int slot = atomicAdd(s_nsel, 1);
        srow[slot] = j; selJ[slot] = j;
      }
      break;
    }
    hist128[tid] = 0u;
    hist128[tid + 64] = 0u;
    if (tid == 0) *s_wtmp = 0;
    asm volatile("s_waitcnt lgkmcnt(0)" ::: "memory");
    for (int s = tid; s < Cc; s += 64) {
      int ch = (int)((cand[rb + s] >> shift) & 127ull);
      atomicAdd(&hist128[ch], 1u);
    }
    asm volatile("s_waitcnt lgkmcnt(0)" ::: "memory");
    unsigned int c0 = hist128[2 * tid];
    unsigned int c1 = hist128[2 * tid + 1];
    unsigned int ps = c0 + c1;
#pragma unroll
    for (int d = 1; d < 64; d <<= 1) {
      unsigned int o = __shfl_down(ps, d);
      if (tid + d < 64) ps += o;
    }
    unsigned int incl = ps;
    unsigned int incln = __shfl_down(incl, 1);
    if (tid == 63) incln = 0u;
    unsigned int smid = incl - c0;
    bool crossHi = (smid >= (unsigned int)needc) && (incln < (unsigned int)needc);
    bool crossLo = (incl >= (unsigned int)needc) && (smid < (unsigned int)needc);
    unsigned long long bal = __ballot(crossHi || crossLo);
    int gl = __ffsll(bal) - 1;
    int hiF = __shfl((int)crossHi, gl);
    int vstar = 2 * gl + hiF;
    unsigned int aboveCh = (unsigned int)__shfl((int)(hiF ? incln : smid), gl);
    int wb = rb ^ 2048;
    for (int s = tid; s < Cc; s += 64) {
      unsigned long long k = cand[rb + s];
      int ch = (int)((k >> shift) & 127ull);
      if (ch > vstar) {
        int j = 16383 - (int)(k & 0x3FFFull);
        int slot = atomicAdd(s_nsel, 1);
        srow[slot] = j; selJ[slot] = j;
      } else if (ch == vstar) {
        int p = atomicAdd(s_wtmp, 1);
        cand[wb + p] = k;
      }
    }
    asm volatile("s_waitcnt lgkmcnt(0)" ::: "memory");
    needc -= (int)aboveCh;
    Cc = *s_wtmp;
    rb = wb;
    shift = (shift >= 7) ? shift - 7 : 0;
  }
}

// ---------------------------------------------------------------------------
// Kernel 1.5: per-row candidate precompute (unchanged, validated).
// hdr[4r] = cnt, +1 = bnd, +2 = shift, +3 = theta (uninhibited count >= 160).
// ---------------------------------------------------------------------------
__global__ __launch_bounds__(1024) void precomp_cand(const float* __restrict__ enc,
                                                     unsigned long long* __restrict__ rec,
                                                     unsigned int* __restrict__ hdr) {
  const int row = blockIdx.x;
  const int tid = threadIdx.x;
  __shared__ unsigned int hA[2048], hB[2048], h2a[2048], h2b[2048];
  __shared__ int s_b1; __shared__ unsigned int s_ab1;
  __shared__ int s_b2; __shared__ unsigned int s_ab2;
  __shared__ int s_cnt;
  __shared__ unsigned int s_omax;
  const float* erow = enc + (size_t)row * H_UNITS;

  unsigned int ob[QPT], eb[QPT];
  for (int i = tid; i < 2048; i += 1024) { hA[i] = 0u; hB[i] = 0u; h2a[i] = 0u; h2b[i] = 0u; }
  if (tid == 0) { s_cnt = 0; s_omax = 0u; }
  unsigned int lmax = 0u;
#pragma unroll
  for (int q = 0; q < QPT; ++q) {
    int j = q * 1024 + tid;
    float e = erow[j];
    eb[q] = __float_as_uint(e);
    ob[q] = orderable(fabsf(e));
    if (ob[q] > lmax) lmax = ob[q];
  }
  __syncthreads();

  atomicMax(&s_omax, lmax);
  unsigned int* hrep = ((tid >> 6) & 1) ? hB : hA;
#pragma unroll
  for (int q = 0; q < QPT; ++q) {
    int b = (int)(ob[q] >> 21);
    atomicAdd(&hrep[SWZ(b)], 1u);
  }
  __syncthreads();
  if (tid < 64) wave_find2048(hA, hB, 1024u, tid, &s_b1, &s_ab1);
  __syncthreads();

  const unsigned int b1 = (unsigned int)s_b1;
  const unsigned int need2 = 1024u - s_ab1;
  unsigned int* h2rep = ((tid >> 6) & 1) ? h2b : h2a;
#pragma unroll
  for (int q = 0; q < QPT; ++q) {
    if ((ob[q] >> 21) == b1) {
      int b = (int)((ob[q] >> 10) & 0x7FFu);
      atomicAdd(&h2rep[SWZ(b)], 1u);
    }
  }
  __syncthreads();
  if (tid < 64) wave_find2048(h2a, h2b, need2, tid, &s_b2, &s_ab2);
  __syncthreads();

  const unsigned int bnd = (b1 << 21) | ((unsigned int)s_b2 << 10);
#pragma unroll
  for (int q = 0; q < QPT; ++q) {
    if (ob[q] >= bnd) {
      int p = atomicAdd(&s_cnt, 1);
      if (p < CAND_MAX)
        rec[(size_t)row * CAND_MAX + p] =
            (((unsigned long long)eb[q]) << 32) | (unsigned long long)(q * 1024 + tid);
    }
  }
  for (int i = tid; i < 2048; i += 1024) { h2a[i] = 0u; h2b[i] = 0u; }
  __syncthreads();

  const unsigned int span = s_omax - bnd;
  const int bitpos = (span == 0u) ? -1 : (31 - __clz((int)span));
  const unsigned int shf = (bitpos > 10) ? (unsigned int)(bitpos - 10) : 0u;
#pragma unroll
  for (int q = 0; q < QPT; ++q) {
    if (ob[q] >= bnd) {
      int bb = (int)((ob[q] - bnd) >> shf);
      atomicAdd(&h2rep[SWZ(bb)], 1u);
    }
  }
  __syncthreads();
  if (tid < 64) wave_find2048(h2a, h2b, PIVOT_NEED, tid, &s_b2, &s_ab2);
  __syncthreads();
  if (tid == 0) {
    hdr[4 * row + 0] = (unsigned int)s_cnt;
    hdr[4 * row + 1] = bnd;
    hdr[4 * row + 2] = shf;
    hdr[4 * row + 3] = bnd + ((unsigned int)s_b2 << shf);  // theta
  }
}

// ---------------------------------------------------------------------------
// Kernel 2: pivot scan (round-5 structure: eager overlapped decay) with
// ballot-aggregated bookkeeping. Fast path per step (3 barriers):
//  A (all): gather <=2 inhib, key o; o>=theta -> ONE s_ccnt atomic per wave
//     (ballot slotting) + h256 spread atomic.                           B1
//  B: wave0: reg-resident 256-bin suffix find -> bstar; one list scan with
//     ballot-positioned emits (>bstar) / tie-collect (==bstar); finish via
//     take-all / tournament / refine. Counts in registers, no LDS atomics.
//     waves1-15 CONCURRENTLY: inhib *= 0.95 as float4 (exact elementwise).B2
//  C: tid<64: inhib[selJ] += 1; zero h256; reset scalars.               B3
// Exactness: selected o >= theta > all non-candidates (r<=|e|<bnd<=theta,
// strict); excluded candidates o < min selected; decay-then-+1 == np
// recurrence. Cc<64 -> tier2; !rowfast or tier2-b1==0 -> tier3 (validated).
// ---------------------------------------------------------------------------
__global__ __launch_bounds__(1024) void scan_cand(const float* __restrict__ enc,
                                                  const unsigned long long* __restrict__ rec,
                                                  const unsigned int* __restrict__ hdr,
                                                  int* __restrict__ seli) {
  const int tid = threadIdx.x;
  __shared__ __align__(16) float inhib[H_UNITS];   // 64 KB
  __shared__ __align__(16) unsigned int h256[256];
  __shared__ unsigned int fine[2048];           // tier2 hist / tier3 replica A
  __shared__ unsigned int histB[2048];          // tier3 replica B / slow3
  __shared__ unsigned long long cand[4096];     // list [0,2048) + ties [2048,4096)
  __shared__ unsigned int hist128[128];
  __shared__ int selJ[64];
  __shared__ int s_b1, s_nsel, s_ccnt, s_c2, s_wtmp;
  __shared__ unsigned int s_above;
  __shared__ int s_b2, s_ab2, s_b3, s_ab3, s_tiecnt;

  // init
#pragma unroll
  for (int q = 0; q < QPT; ++q) inhib[q * 1024 + tid] = 0.0f;
  fine[tid] = 0u; fine[1024 + tid] = 0u;
  histB[tid] = 0u; histB[1024 + tid] = 0u;
  if (tid < 256) h256[tid] = 0u;
  if (tid == 0) { s_nsel = 0; s_ccnt = 0; s_c2 = 0; s_wtmp = 0; }
  __syncthreads();

  unsigned long long pre0 = rec[tid];
  unsigned long long pre1 = rec[1024 + tid];
  unsigned int preCnt = hdr[0];
  unsigned int preBnd = hdr[1];
  unsigned int preShf = hdr[2];
  unsigned int preTheta = hdr[3];

  const int lane = tid & 63;
  const unsigned long long ltm = (1ull << lane) - 1ull;

  for (int t = 0; t < B_ROWS; ++t) {
    int* srow = seli + t * 64;
    const unsigned long long r0 = pre0, r1 = pre1;
    const int cnt = (int)preCnt;
    const unsigned int bnd = preBnd;
    const int shift = (int)preShf;
    const unsigned int theta = preTheta;
    const int hs = shift + 3;

    const int tn = (t + 1 < B_ROWS) ? (t + 1) : t;
    pre0 = rec[(size_t)tn * CAND_MAX + tid];
    pre1 = rec[(size_t)tn * CAND_MAX + 1024 + tid];
    preCnt = hdr[4 * tn + 0];
    preBnd = hdr[4 * tn + 1];
    preShf = hdr[4 * tn + 2];
    preTheta = hdr[4 * tn + 3];

    const bool rowfast = (cnt <= CAND_MAX);

    // ---- phase A: keys + ballot-aggregated list append ----
    bool v0 = false, v1 = false;
    unsigned int o0 = 0u, o1 = 0u;
    int j0 = 0, j1 = 0;
    unsigned long long key0 = 0ull, key1 = 0ull;
    unsigned int bin0 = 0u, bin1 = 0u;
    bool pred0 = false, pred1 = false;
    if (rowfast) {
      v0 = (tid < cnt);
      v1 = (1024 + tid < cnt);
      if (v0) {
        j0 = (int)(r0 & 0xFFFFull);
        float e = __uint_as_float((unsigned int)(r0 >> 32));
        float rr = __fmul_rn(fabsf(e), __fsub_rn(1.0f, inhib[j0]));  // np-exact
        o0 = orderable(rr);
        pred0 = (o0 >= theta);
        if (pred0) {
          key0 = (((unsigned long long)(o0 - theta)) << 14) | (unsigned long long)(16383 - j0);
          bin0 = (o0 - theta) >> hs;
        }
      }
      if (v1) {
        j1 = (int)(r1 & 0xFFFFull);
        float e = __uint_as_float((unsigned int)(r1 >> 32));
        float rr = __fmul_rn(fabsf(e), __fsub_rn(1.0f, inhib[j1]));
        o1 = orderable(rr);
        pred1 = (o1 >= theta);
        if (pred1) {
          key1 = (((unsigned long long)(o1 - theta)) << 14) | (unsigned long long)(16383 - j1);
          bin1 = (o1 - theta) >> hs;
        }
      }
      // one s_ccnt atomic per wave; intra-wave slots via ballot prefix
      unsigned long long bal0 = __ballot(pred0);
      unsigned long long bal1 = __ballot(pred1);
      int c0 = __popcll(bal0), c1 = __popcll(bal1);
      int base = 0;
      if (lane == 0 && (c0 + c1) > 0) base = atomicAdd(&s_ccnt, c0 + c1);
      base = __shfl(base, 0);
      if (pred0) {
        cand[base + __popcll(bal0 & ltm)] = key0;
        atomicAdd(&h256[bin0], 1u);
      }
      if (pred1) {
        cand[base + c0 + __popcll(bal1 & ltm)] = key1;
        atomicAdd(&h256[bin1], 1u);
      }
    }
    __syncthreads();  // B1

    const int Cc = s_ccnt;
    const bool fastok = rowfast && (Cc >= 64);

    if (fastok) {
      // ---- phase B: wave0 select (register-accounted) || waves1-15 decay ----
      if (tid < 64) {
        uint4 c4 = reinterpret_cast<const uint4*>(h256)[tid];
        unsigned int lsum = c4.x + c4.y + c4.z + c4.w;
        unsigned int si = lsum;
#pragma unroll
        for (int d = 1; d < 64; d <<= 1) {
          unsigned int o = __shfl_down(si, d);
          if (tid + d < 64) si += o;
        }
        unsigned int snext = __shfl_down(si, 1);
        if (tid == 63) snext = 0u;
        bool cross = (si >= 64u) && (snext < 64u);
        unsigned long long bal = __ballot(cross);
        int g = __ffsll(bal) - 1;
        unsigned int acc = snext;
        int bl = tid * 4;
        if (acc + c4.w >= 64u) { bl = tid * 4 + 3; }
        else {
          acc += c4.w;
          if (acc + c4.z >= 64u) { bl = tid * 4 + 2; }
          else {
            acc += c4.z;
            if (acc + c4.y >= 64u) { bl = tid * 4 + 1; }
            else { bl = tid * 4; }
          }
        }
        const unsigned int bstar = (unsigned int)__shfl(bl, g);
        // single scan: ballot-positioned emit(>b*) and tie-collect(==b*)
        const int ksh = 14 + hs;
        int nsel = 0, ntie = 0;
        for (int s0 = 0; s0 < Cc; s0 += 64) {
          int s = s0 + tid;
          bool inr = (s < Cc);
          unsigned long long k = inr ? cand[s] : 0ull;
          unsigned int bk = (unsigned int)(k >> ksh);
          bool em = inr && (bk > bstar);
          bool ti = inr && (bk == bstar);
          unsigned long long balE = __ballot(em);
          unsigned long long balT = __ballot(ti);
          if (em) {
            int p = nsel + __popcll(balE & ltm);
            int j = 16383 - (int)(k & 0x3FFFull);
            srow[p] = j; selJ[p] = j;
          }
          if (ti) {
            int p = ntie + __popcll(balT & ltm);
            cand[2048 + p] = k;
          }
          nsel += __popcll(balE);
          ntie += __popcll(balT);
        }
        asm volatile("s_waitcnt lgkmcnt(0)" ::: "memory");
        const int tneed = 64 - nsel;   // ntie >= tneed always (bstar crossing)
        const int Cc2 = ntie;
        if (Cc2 <= tneed) {
          for (int s = tid; s < Cc2; s += 64) {
            unsigned long long k = cand[2048 + s];
            int j = 16383 - (int)(k & 0x3FFFull);
            srow[nsel + s] = j; selJ[nsel + s] = j;
          }
        } else if (Cc2 <= 64 && tneed <= 16) {
          bool alive = (tid < Cc2);
          unsigned long long myk = alive ? cand[2048 + tid] : 0ull;
          for (int r = 0; r < tneed; ++r) {
            unsigned long long v = myk;
#pragma unroll
            for (int d = 32; d >= 1; d >>= 1) {
              unsigned long long o = __shfl_down(v, d);
              if (o > v) v = o;
            }
            v = __shfl(v, 0);
            if (alive && myk == v) {
              int j = 16383 - (int)(myk & 0x3FFFull);
              srow[nsel + r] = j; selJ[nsel + r] = j;
              alive = false; myk = 0ull;
            }
          }
        } else {
          if (lane == 0) s_nsel = nsel;
          asm volatile("s_waitcnt lgkmcnt(0)" ::: "memory");
          wave_refine_pp(cand, hist128, Cc2, tneed, shift + 10, srow, selJ,
                         &s_nsel, &s_wtmp, 2048);
          if (lane == 0) s_wtmp = 0;
        }
      } else {
        // waves 1-15: decay ALL inhibition as float4 (exact elementwise)
        float4* p4 = reinterpret_cast<float4*>(inhib);
        for (int i = tid - 64; i < H_UNITS / 4; i += 960) {
          float4 v = p4[i];
          v.x = __fmul_rn(v.x, 0.95f);
          v.y = __fmul_rn(v.y, 0.95f);
          v.z = __fmul_rn(v.z, 0.95f);
          v.w = __fmul_rn(v.w, 0.95f);
          p4[i] = v;
        }
      }
      __syncthreads();  // B2

      // ---- phase C: +1 on selected (post-decay), housekeeping ----
      if (tid < 64) {
        int j = selJ[tid];
        inhib[j] = __fadd_rn(inhib[j], 1.0f);
      } else if (tid < 320) {
        h256[tid - 64] = 0u;
      } else if (tid == 320) {
        s_ccnt = 0;
      } else if (tid == 321) {
        s_nsel = 0;
      }
      __syncthreads();  // B3
      continue;
    }

    // =================== TIER 2 / TIER 3 (rare, validated) ===================
    bool do_fullrow = !rowfast;
    if (rowfast) {
      // TIER 2: candidate histogram on register keys (pre-decay inhib)
      if (v0) {
        unsigned int bb = (o0 >= bnd) ? ((o0 - bnd) >> shift) : 0u;
        atomicAdd(&fine[SWZ((int)bb)], 1u);
      }
      if (v1) {
        unsigned int bb = (o1 >= bnd) ? ((o1 - bnd) >> shift) : 0u;
        atomicAdd(&fine[SWZ((int)bb)], 1u);
      }
      __syncthreads();
      if (tid < 64) wave_find_single(fine, 64u, tid, &s_b1, &s_above);
      __syncthreads();
      const int b1v = s_b1;
      if (b1v > 0) {
        const unsigned int basev = bnd + ((unsigned int)b1v << shift);
        if (v0) {
          unsigned int bb = (o0 >= bnd) ? ((o0 - bnd) >> shift) : 0u;
          if ((int)bb > b1v) {
            int slot = atomicAdd(&s_nsel, 1);
            srow[slot] = j0; selJ[slot] = j0;
          } else if ((int)bb == b1v) {
            int p = atomicAdd(&s_c2, 1);
            cand[2048 + p] = (((unsigned long long)(o0 - basev)) << 14) | (unsigned long long)(16383 - j0);
          }
        }
        if (v1) {
          unsigned int bb = (o1 >= bnd) ? ((o1 - bnd) >> shift) : 0u;
          if ((int)bb > b1v) {
            int slot = atomicAdd(&s_nsel, 1);
            srow[slot] = j1; selJ[slot] = j1;
          } else if ((int)bb == b1v) {
            int p = atomicAdd(&s_c2, 1);
            cand[2048 + p] = (((unsigned long long)(o1 - basev)) << 14) | (unsigned long long)(16383 - j1);
          }
        }
        __syncthreads();
        const int Cc2 = s_c2;
        if (tid < 64)
          wave_refine_pp(cand, hist128, Cc2, 64 - s_nsel, shift + 7, srow, selJ,
                         &s_nsel, &s_wtmp, 2048);
        __syncthreads();
      } else {
        fine[tid] = 0u; fine[1024 + tid] = 0u;
        __syncthreads();
        do_fullrow = true;
      }
    }

    if (do_fullrow) {
      // TIER 3: full-row (pre-decay inhib)
      const float* erow = enc + (size_t)t * H_UNITS;
      unsigned int ok[QPT];
#pragma unroll
      for (int q = 0; q < QPT; ++q) {
        int j = q * 1024 + tid;
        float e = erow[j];
        float rr = __fmul_rn(fabsf(e), __fsub_rn(1.0f, inhib[j]));
        ok[q] = orderable(rr);
      }
      __syncthreads();
      unsigned int* hrep = ((tid >> 6) & 1) ? histB : fine;
#pragma unroll
      for (int q = 0; q < QPT; ++q) {
        int b = (int)(ok[q] >> 21);
        atomicAdd(&hrep[SWZ(b)], 1u);
      }
      __syncthreads();
      if (tid < 64) wave_find2048(fine, histB, 64u, tid, &s_b1, &s_above);
      __syncthreads();
      const unsigned int fb1 = (unsigned int)s_b1;
#pragma unroll
      for (int q = 0; q < QPT; ++q) {
        unsigned int o = ok[q];
        unsigned int bb = o >> 21;
        int j = q * 1024 + tid;
        if (bb > fb1) {
          int slot = atomicAdd(&s_nsel, 1);
          srow[slot] = j; selJ[slot] = j;
        } else if (bb == fb1) {
          int p = atomicAdd(&s_c2, 1);
          if (p < 2048)
            cand[p] = (((unsigned long long)(o - (fb1 << 21))) << 14) | (unsigned long long)(16383 - j);
        }
      }
      __syncthreads();
      const int Cc0 = s_c2;
      if (Cc0 <= 2048) {
        if (tid < 64)
          wave_refine_pp(cand, hist128, Cc0, 64 - s_nsel, 28, srow, selJ,
                         &s_nsel, &s_wtmp, 0);
        __syncthreads();
      } else {
        // slow 3-pass (proven)
        int need2 = 64 - s_nsel;
        for (int i = tid; i < 2048; i += 1024) fine[i] = 0u;
        histB[tid] = 0u; histB[1024 + tid] = 0u;
        if (tid == 0) s_tiecnt = 0;
        __syncthreads();
#pragma unroll
        for (int q = 0; q < QPT; ++q)
          if ((ok[q] >> 21) == fb1) atomicAdd(&fine[(ok[q] >> 10) & 0x7FFu], 1u);
        __syncthreads();
        suffix_find(fine, 32, need2, tid, &s_b2, &s_ab2);
        __syncthreads();
        const unsigned int pfx = (fb1 << 21) | ((unsigned int)s_b2 << 10);
        const int need3 = need2 - s_ab2;
#pragma unroll
        for (int q = 0; q < QPT; ++q)
          if ((ok[q] & 0xFFFFFC00u) == pfx) atomicAdd(&histB[ok[q] & 0x3FFu], 1u);
        __syncthreads();
        suffix_find(histB, 16, need3, tid, &s_b3, &s_ab3);
        __syncthreads();
        const unsigned int ostar = pfx | (unsigned int)s_b3;
        const int tneed = need3 - s_ab3;
        int* tl = (int*)cand;
#pragma unroll
        for (int q = 0; q < QPT; ++q) {
          unsigned int o = ok[q];
          int j = q * 1024 + tid;
          if (o > ostar && (o >> 21) == fb1) {
            int slot = atomicAdd(&s_nsel, 1);
            srow[slot] = j; selJ[slot] = j;
          } else if (o == ostar) {
            int p = atomicAdd(&s_tiecnt, 1);
            if (p < 1024) tl[p] = j;
          }
        }
        __syncthreads();
        if (tid == 0) {
          int tc = s_tiecnt; if (tc > 1024) tc = 1024;
          for (int k = 0; k < tneed; ++k) {
            int bi = 0x7FFFFFFF, bpos = 0;
            for (int i = 0; i < tc; ++i) {
              int v = tl[i];
              if (v < bi) { bi = v; bpos = i; }
            }
            tl[bpos] = 0x7FFFFFFF;
            selJ[64 - tneed + k] = bi;
            srow[64 - tneed + k] = bi;
          }
        }
        __syncthreads();
      }
    }

    // ---- tier common tail: decay all, clean LDS, then +1 ----
#pragma unroll
    for (int q = 0; q < QPT; ++q) {
      int j = q * 1024 + tid;
      inhib[j] = __fmul_rn(inhib[j], 0.95f);
    }
    fine[tid] = 0u; fine[1024 + tid] = 0u;
    histB[tid] = 0u; histB[1024 + tid] = 0u;
    if (tid < 256) h256[tid] = 0u;
    if (tid == 256) { s_ccnt = 0; }
    if (tid == 257) { s_nsel = 0; }
    if (tid == 258) { s_c2 = 0; }
    if (tid == 259) { s_wtmp = 0; }
    __syncthreads();
    if (tid < 64) {
      int j = selJ[tid];
      inhib[j] = __fadd_rn(inhib[j], 1.0f);
    }
    __syncthreads();
  }
}

// ---------------------------------------------------------------------------
// Kernel 2-OLD (ws-gate fallback): validated full-row scan (unchanged).
// ---------------------------------------------------------------------------
__global__ __launch_bounds__(1024) void scan_radix(const float* __restrict__ enc,
                                                   int* __restrict__ seli) {
  const int tid = threadIdx.x;
  __shared__ unsigned int histA[2048];
  __shared__ unsigned int histB[2048];
  __shared__ unsigned int hist128[128];
  __shared__ unsigned int bmap[2][512];
  __shared__ unsigned long long cand[4096];
  __shared__ int s_b1, s_nsel, s_ccnt, s_wtmp;
  __shared__ int s_b2, s_ab2, s_b3, s_ab3, s_tiecnt;
  __shared__ unsigned int s_abU;

  float iv[QPT];
  float ec[QPT];
#pragma unroll
  for (int q = 0; q < QPT; ++q) iv[q] = 0.0f;
#pragma unroll
  for (int q = 0; q < QPT; ++q) ec[q] = enc[q * 1024 + tid];

  for (int t = 0; t < B_ROWS; ++t) {
    const int cur = t & 1;
    unsigned int* bm = bmap[cur];
    int* srow = seli + t * 64;

    for (int i = tid; i < 2048; i += 1024) { histA[i] = 0u; histB[i] = 0u; }
    if (tid < 512) bm[tid] = 0u;
    if (tid == 0) { s_nsel = 0; s_ccnt = 0; }
    unsigned int ok[QPT];
#pragma unroll
    for (int q = 0; q < QPT; ++q) {
      float r = __fmul_rn(fabsf(ec[q]), __fsub_rn(1.0f, iv[q]));
      ok[q] = orderable(r);
    }
    __syncthreads();

    const int tn = (t + 1 < B_ROWS) ? (t + 1) : t;
    const float* nrow = enc + (size_t)tn * H_UNITS;
    float en[QPT];
#pragma unroll
    for (int q = 0; q < QPT; ++q) en[q] = nrow[q * 1024 + tid];

    unsigned int* hrep = ((tid >> 6) & 1) ? histB : histA;
#pragma unroll
    for (int q = 0; q < QPT; ++q) {
      int b = (int)(ok[q] >> 21);
      atomicAdd(&hrep[SWZ(b)], 1u);
    }
    __syncthreads();

    if (tid < 64) wave_find2048(histA, histB, 64u, tid, &s_b1, &s_abU);
    __syncthreads();

    const unsigned int b1 = (unsigned int)s_b1;
#pragma unroll
    for (int q = 0; q < QPT; ++q) {
      unsigned int o = ok[q];
      unsigned int bb = o >> 21;
      if (bb >= b1) {
        int j = q * 1024 + tid;
        if (bb > b1) {
          int slot = atomicAdd(&s_nsel, 1);
          srow[slot] = j;
          atomicOr(&bm[j >> 5], 1u << (j & 31));
        } else {
          int p = atomicAdd(&s_ccnt, 1);
          if (p < 2048)
            cand[p] = (((unsigned long long)o) << 14) | (unsigned long long)(16383 - j);
        }
      }
    }
    __syncthreads();

    const int Cc0 = s_ccnt;
    if (Cc0 <= 2048) {
      if (tid < 64) {
        int needc = 64 - s_nsel;
        int Cc = Cc0;
        int shift = 28;
        int rb = 0;
        while (true) {
          if (Cc <= needc) {
            for (int s = tid; s < Cc; s += 64) {
              unsigned long long k = cand[rb + s];
              int j = 16383 - (int)(k & 0x3FFFull);
              int slot = atomicAdd(&s_nsel, 1);
              srow[slot] = j;
              atomicOr(&bm[j >> 5], 1u << (j & 31));
            }
            break;
          }
          hist128[tid] = 0u;
          hist128[tid + 64] = 0u;
          if (tid == 0) s_wtmp = 0;
          asm volatile("s_waitcnt lgkmcnt(0)" ::: "memory");
          for (int s = tid; s < Cc; s += 64) {
            int ch = (int)((cand[rb + s] >> shift) & 127ull);
            atomicAdd(&hist128[ch], 1u);
          }
          asm volatile("s_waitcnt lgkmcnt(0)" ::: "memory");
          unsigned int c0 = hist128[2 * tid];
          unsigned int c1 = hist128[2 * tid + 1];
          unsigned int ps = c0 + c1;
#pragma unroll
          for (int d = 1; d < 64; d <<= 1) {
            unsigned int o = __shfl_down(ps, d);
            if (tid + d < 64) ps += o;
          }
          unsigned int incl = ps;
          unsigned int incln = __shfl_down(incl, 1);
          if (tid == 63) incln = 0u;
          unsigned int smid = incl - c0;
          bool crossHi = (smid >= (unsigned int)needc) && (incln < (unsigned int)needc);
          bool crossLo = (incl >= (unsigned int)needc) && (smid < (unsigned int)needc);
          unsigned long long bal = __ballot(crossHi || crossLo);
          int gl = __ffsll(bal) - 1;
          int hiF = __shfl((int)crossHi, gl);
          int vstar = 2 * gl + hiF;
          unsigned int aboveCh = (unsigned int)__shfl((int)(hiF ? incln : smid), gl);
          int wb = rb ^ 2048;
          for (int s = tid; s < Cc; s += 64) {
            unsigned long long k = cand[rb + s];
            int ch = (int)((k >> shift) & 127ull);
            if (ch > vstar) {
              int j = 16383 - (int)(k & 0x3FFFull);
              int slot = atomicAdd(&s_nsel, 1);
              srow[slot] = j;
              atomicOr(&bm[j >> 5], 1u << (j & 31));
            } else if (ch == vstar) {
              int p = atomicAdd(&s_wtmp, 1);
              cand[wb + p] = k;
            }
          }
          asm volatile("s_waitcnt lgkmcnt(0)" ::: "memory");
          needc -= (int)aboveCh;
          Cc = s_wtmp;
          rb = wb;
          shift = (shift >= 7) ? shift - 7 : 0;
        }
      }
    } else {
      int need2 = 64 - s_nsel;
      for (int i = tid; i < 2048; i += 1024) histA[i] = 0u;
      histB[tid] = 0u;
      if (tid == 0) s_tiecnt = 0;
      __syncthreads();
#pragma unroll
      for (int q = 0; q < QPT; ++q)
        if ((ok[q] >> 21) == b1) atomicAdd(&histA[(ok[q] >> 10) & 0x7FFu], 1u);
      __syncthreads();
      suffix_find(histA, 32, need2, tid, &s_b2, &s_ab2);
      __syncthreads();
      const unsigned int pfx = (b1 << 21) | ((unsigned int)s_b2 << 10);
      const int need3 = need2 - s_ab2;
#pragma unroll
      for (int q = 0; q < QPT; ++q)
        if ((ok[q] & 0xFFFFFC00u) == pfx) atomicAdd(&histB[ok[q] & 0x3FFu], 1u);
      __syncthreads();
      suffix_find(histB, 16, need3, tid, &s_b3, &s_ab3);
      __syncthreads();
      const unsigned int ostar = pfx | (unsigned int)s_b3;
      const int tneed = need3 - s_ab3;
      int* tl = (int*)cand;
#pragma unroll
      for (int q = 0; q < QPT; ++q) {
        unsigned int o = ok[q];
        int j = q * 1024 + tid;
        if (o > ostar && (o >> 21) == b1) {
          int slot = atomicAdd(&s_nsel, 1);
          srow[slot] = j;
          atomicOr(&bm[j >> 5], 1u << (j & 31));
        } else if (o == ostar) {
          int p = atomicAdd(&s_tiecnt, 1);
          if (p < 1024) tl[p] = j;
        }
      }
      __syncthreads();
      if (tid == 0) {
        int tc = s_tiecnt; if (tc > 1024) tc = 1024;
        for (int k = 0; k < tneed; ++k) {
          int bi = 0x7FFFFFFF, bpos = 0;
          for (int i = 0; i < tc; ++i) {
            int v = tl[i];
            if (v < bi) { bi = v; bpos = i; }
          }
          tl[bpos] = 0x7FFFFFFF;
          bmap[cur][bi >> 5] |= (1u << (bi & 31));
          srow[64 - tneed + k] = bi;
        }
      }
    }
    __syncthreads();

#pragma unroll
    for (int q = 0; q < QPT; ++q) {
      int j = q * 1024 + tid;
      float m = ((bm[j >> 5] >> (j & 31)) & 1u) ? 1.0f : 0.0f;
      iv[q] = __fadd_rn(__fmul_rn(iv[q], 0.95f), m);
      ec[q] = en[q];
    }
    __syncthreads();
  }
}

// ---------------------------------------------------------------------------
// Kernel 3: final top-64 over filtered = enc * mask (unchanged, validated).
// ---------------------------------------------------------------------------
__global__ __launch_bounds__(1024) void final_brute(const int* __restrict__ seli,
                                                    float* __restrict__ out) {
  const int row = blockIdx.x;
  const int tid = threadIdx.x;
  __shared__ unsigned long long wmax[16];
  __shared__ unsigned long long s_win;
  __shared__ int wlist[64];
  __shared__ unsigned int bmap[512];
  const float* erow = out + (size_t)row * H_UNITS;

  if (tid < 512) bmap[tid] = 0u;
  __syncthreads();
  if (tid < 64) {
    int idx = seli[row * 64 + tid];
    atomicOr(&bmap[idx >> 5], 1u << (idx & 31));
  }
  __syncthreads();

  unsigned long long key[16];
  unsigned long long lmax = 0ull;
#pragma unroll
  for (int q = 0; q < 16; ++q) {
    int j = q * 1024 + tid;
    float e = erow[j];
    bool sel = (bmap[j >> 5] >> (j & 31)) & 1u;
    unsigned int eb = __float_as_uint(e);
    float f = __uint_as_float(sel ? eb : (eb & 0x80000000u));  // ±0 keeps sign
    unsigned long long k = make_key(f, j);
    key[q] = k;
    if (k > lmax) lmax = k;
  }
  __syncthreads();

  float4 z = make_float4(0.0f, 0.0f, 0.0f, 0.0f);
  float4* o4 = reinterpret_cast<float4*>(out + (size_t)row * H_UNITS);
  for (int i = tid; i < H_UNITS / 4; i += 1024) o4[i] = z;
  __syncthreads();

  for (int round = 0; round < 64; ++round) {
    unsigned long long v = lmax;
#pragma unroll
    for (int d = 32; d >= 1; d >>= 1) {
      unsigned long long o = __shfl_down(v, d);
      if (o > v) v = o;
    }
    if ((tid & 63) == 0) wmax[tid >> 6] = v;
    __syncthreads();
    if (tid == 0) {
      unsigned long long m = wmax[0];
#pragma unroll
      for (int w = 1; w < 16; ++w)
        if (wmax[w] > m) m = wmax[w];
      s_win = m;
      wlist[round] = 16383 - (int)(m & 0x3FFFull);
    }
    __syncthreads();
    unsigned long long Wk = s_win;
    if (lmax == Wk) {
      unsigned long long nm = 0ull;
#pragma unroll
      for (int q = 0; q < 16; ++q) {
        unsigned long long k = key[q];
        if (k < Wk && k > nm) nm = k;
      }
      lmax = nm;
    }
  }
  __syncthreads();
  if (tid < 64) out[(size_t)row * H_UNITS + wlist[tid]] = 1.0f;
}

// ---------------------------------------------------------------------------
extern "C" void kernel_launch(void* const* d_in, const int* in_sizes, int n_in,
                              void* d_out, int out_size, void* d_ws, size_t ws_size,
                              hipStream_t stream) {
  const float* inputs = (const float*)d_in[0];   // [512][2048] fp32
  const float* W = (const float*)d_in[1];        // [16384][2048] fp32
  float* out = (float*)d_out;                    // [512][16384] fp32 -- also enc scratch
  char* ws = (char*)d_ws;

  // ws layout: [0] seli 128KB | [131072] hdr 8KB | [139264] rec 8MB
  int* seli = (int*)(ws);
  unsigned int* hdr = (unsigned int*)(ws + 131072);
  unsigned long long* rec = (unsigned long long*)(ws + 139264);
  const size_t WS_NEEDED = 139264 + (size_t)B_ROWS * CAND_MAX * 8;  // 8,527,872

  float* enc = out;  // encoding scratch lives in d_out

  gemm_kernel<<<dim3(H_UNITS / 64, B_ROWS / 64), 256, 0, stream>>>(inputs, W, enc);
  if (ws_size >= WS_NEEDED) {
    precomp_cand<<<B_ROWS, 1024, 0, stream>>>(enc, rec, hdr);
    scan_cand<<<1, 1024, 0, stream>>>(enc, rec, hdr, seli);
  } else {
    scan_radix<<<1, 1024, 0, stream>>>(enc, seli);
  }
  final_brute<<<B_ROWS, 1024, 0, stream>>>(seli, out);
}